// Round 1
// baseline (256.529 us; speedup 1.0000x reference)
//
#include <hip/hip_runtime.h>
#include <cmath>

#define DIM 384
#define IMG 112
#define IMG2 (IMG*IMG)          // 12544
#define FINALN 16
#define PATCH 49
#define DROP_P 0.2f

// ws layout (floats):
//   [0, 100352)          : W   = per-pixel channel-weighted sum (8*112*112)
//   [100352, 200704)     : attn = 2048 patches * 49

// ---------------- Kernel A: W[b,y,x] = sum_c hr[b,c,y,x] * aw[c] ----------------
__global__ __launch_bounds__(256) void kA(const float* __restrict__ hr,
                                          const float* __restrict__ aw,
                                          float* __restrict__ W) {
    __shared__ float s_aw[DIM];
    int tid = threadIdx.x;
    for (int i = tid; i < DIM; i += 256) s_aw[i] = aw[i];
    __syncthreads();
    int pid = blockIdx.x * 256 + tid;         // 392*256 = 100352 exactly
    int b   = pid / IMG2;
    int rem = pid - b * IMG2;
    const float* p = hr + (b * DIM) * IMG2 + rem;
    float a0 = 0.f, a1 = 0.f, a2 = 0.f, a3 = 0.f;
    #pragma unroll 2
    for (int c = 0; c < DIM; c += 4) {
        a0 += p[(c + 0) * IMG2] * s_aw[c + 0];
        a1 += p[(c + 1) * IMG2] * s_aw[c + 1];
        a2 += p[(c + 2) * IMG2] * s_aw[c + 2];
        a3 += p[(c + 3) * IMG2] * s_aw[c + 3];
    }
    W[pid] = (a0 + a1) + (a2 + a3);
}

// ---------------- Kernel B: per-patch masked softmax -> attn ----------------
__global__ __launch_bounds__(256) void kB(const float* __restrict__ W,
                                          const float* __restrict__ du,
                                          const float* __restrict__ ab,
                                          const float* __restrict__ wmat,
                                          const float* __restrict__ bmat,
                                          float* __restrict__ attn) {
    __shared__ float s_w[PATCH], s_b[PATCH];
    int tid = threadIdx.x;
    if (tid < PATCH) { s_w[tid] = wmat[tid]; s_b[tid] = bmat[tid]; }
    __syncthreads();
    int t = blockIdx.x * 256 + tid;           // 8 blocks -> 2048 patches
    int b = t >> 8;
    int hw = t & 255;
    int h = hw >> 4;
    int w = hw & 15;
    float mask = (du[t] > DROP_P) ? 1.0f : 0.0f;
    float abv  = ab[0];
    const float* Wp = W + b * IMG2 + (h * 7) * IMG + w * 7;
    float l[PATCH];
    float m = -1e30f;
    #pragma unroll
    for (int i = 0; i < 7; ++i) {
        #pragma unroll
        for (int j = 0; j < 7; ++j) {
            int p = i * 7 + j;
            float logit = Wp[i * IMG + j] + abv;
            float al = fmaf(logit * mask, s_w[p], s_b[p]);
            l[p] = al;
            m = fmaxf(m, al);
        }
    }
    float s = 0.f;
    #pragma unroll
    for (int p = 0; p < PATCH; ++p) { float e = __expf(l[p] - m); l[p] = e; s += e; }
    float inv = 1.0f / s;
    float* ap = attn + t * PATCH;
    #pragma unroll
    for (int p = 0; p < PATCH; ++p) ap[p] = l[p] * inv;
}

// ---------------- Kernel C: out[b,c,h,w] = sum_p patch[p][c] * attn[p] ----------------
// block = (b, h, cg) with cg = group of 8 channels; 8*16*48 = 6144 blocks
__global__ __launch_bounds__(256) void kC(const float* __restrict__ hr,
                                          const float* __restrict__ attn,
                                          float* __restrict__ out) {
    int blk = blockIdx.x;
    int cg  = blk % 48;
    int h   = (blk / 48) % FINALN;
    int b   = blk / (48 * FINALN);

    __shared__ float s_attn[FINALN * PATCH];   // 784
    __shared__ float s_col[2][IMG];            // column partial sums, 2 channels/iter

    int tid = threadIdx.x;
    const float* abase = attn + (b * 256 + h * 16) * PATCH;  // 784 contiguous floats
    for (int i = tid; i < FINALN * PATCH; i += 256) s_attn[i] = abase[i];
    __syncthreads();

    int c_local = tid / IMG;     // 0 or 1 for tid < 224
    int x       = tid - c_local * IMG;
    int w       = x / 7;
    int j       = x - w * 7;

    for (int it = 0; it < 4; ++it) {
        if (tid < 2 * IMG) {
            int c = cg * 8 + it * 2 + c_local;
            const float* p  = hr + (size_t)(b * DIM + c) * IMG2 + (h * 7) * IMG + x;
            const float* ap = s_attn + w * PATCH + j;
            float acc = 0.f;
            #pragma unroll
            for (int i = 0; i < 7; ++i) acc += p[i * IMG] * ap[i * 7];
            s_col[c_local][x] = acc;
        }
        __syncthreads();
        if (tid < 32) {
            int cc = tid >> 4;
            int ww = tid & 15;
            float s = 0.f;
            #pragma unroll
            for (int j2 = 0; j2 < 7; ++j2) s += s_col[cc][ww * 7 + j2];
            int c2 = cg * 8 + it * 2 + cc;
            out[((b * DIM + c2) * FINALN + h) * FINALN + ww] = s;
        }
        __syncthreads();
    }
}

extern "C" void kernel_launch(void* const* d_in, const int* in_sizes, int n_in,
                              void* d_out, int out_size, void* d_ws, size_t ws_size,
                              hipStream_t stream) {
    const float* hr   = (const float*)d_in[0];
    // d_in[1] = guidance (unused by reference)
    const float* du   = (const float*)d_in[2];
    const float* aw   = (const float*)d_in[3];
    const float* ab   = (const float*)d_in[4];
    const float* wmat = (const float*)d_in[5];
    const float* bmat = (const float*)d_in[6];
    float* out = (float*)d_out;

    float* W    = (float*)d_ws;            // 100352 floats
    float* attn = W + 8 * IMG2;            // 100352 floats (2048*49)

    kA<<<392, 256, 0, stream>>>(hr, aw, W);
    kB<<<8, 256, 0, stream>>>(W, du, ab, wmat, bmat, attn);
    kC<<<6144, 256, 0, stream>>>(hr, attn, out);
}

// Round 2
// 255.579 us; speedup vs baseline: 1.0037x; 1.0037x over previous
//
#include <hip/hip_runtime.h>
#include <cmath>

#define DIM 384
#define IMG 112
#define IMG2 (IMG*IMG)          // 12544
#define QIMG2 (IMG2/4)          // 3136 float4 per image
#define FINALN 16
#define PATCH 49
#define DROP_P 0.2f
#define NS 8                    // channel splits in kA
#define CPS (DIM/NS)            // 48 channels per split

// ws layout (floats):
//   [0, 802816)           : Wp  = partial pixel sums, 8 splits * 100352 pixels
//   [802816, 903168)      : attn = 2048 patches * 49

// ---- Kernel A: partial W: Wp[s][pix] = sum_{c in split s} hr[b,c,pix]*aw[c] ----
// grid (98, 8): x -> pixel-quad, y -> channel split. float4 loads.
__global__ __launch_bounds__(256) void kA(const float4* __restrict__ hr4,
                                          const float* __restrict__ aw,
                                          float4* __restrict__ Wp4) {
    __shared__ float s_aw[CPS];
    int tid = threadIdx.x;
    int s = blockIdx.y;
    if (tid < CPS) s_aw[tid] = aw[s * CPS + tid];
    __syncthreads();
    int pid4 = blockIdx.x * 256 + tid;        // 98*256 = 25088
    int b    = pid4 / QIMG2;
    int rem  = pid4 - b * QIMG2;
    const float4* p = hr4 + (size_t)(b * DIM + s * CPS) * QIMG2 + rem;
    float a0 = 0.f, a1 = 0.f, a2 = 0.f, a3 = 0.f;
    #pragma unroll 12
    for (int c = 0; c < CPS; ++c) {
        float4 v = p[(size_t)c * QIMG2];
        float w = s_aw[c];
        a0 = fmaf(v.x, w, a0);
        a1 = fmaf(v.y, w, a1);
        a2 = fmaf(v.z, w, a2);
        a3 = fmaf(v.w, w, a3);
    }
    Wp4[s * 25088 + pid4] = make_float4(a0, a1, a2, a3);
}

// ---- Kernel B: wave-per-patch softmax. Sums the NS partials, applies mask/affine,
// 64-lane shuffle softmax over 49 positions. 512 blocks * 256 (4 waves = 4 patches).
__global__ __launch_bounds__(256) void kB(const float* __restrict__ Wp,
                                          const float* __restrict__ du,
                                          const float* __restrict__ ab,
                                          const float* __restrict__ wmat,
                                          const float* __restrict__ bmat,
                                          float* __restrict__ attn) {
    int tid  = threadIdx.x;
    int lane = tid & 63;
    int t    = blockIdx.x * 4 + (tid >> 6);   // patch id, 0..2047
    int b = t >> 8;
    int h = (t >> 4) & 15;
    int w = t & 15;
    float mask = (du[t] > DROP_P) ? 1.0f : 0.0f;
    float abv  = ab[0];

    float al = -1e30f;
    float e  = 0.f;
    if (lane < PATCH) {
        int i = lane / 7;
        int j = lane - i * 7;
        int pix = b * IMG2 + (7 * h + i) * IMG + 7 * w + j;
        float logit = abv;
        #pragma unroll
        for (int s = 0; s < NS; ++s) logit += Wp[s * 100352 + pix];
        al = fmaf(logit * mask, wmat[lane], bmat[lane]);
    }
    // wave max
    float m = al;
    #pragma unroll
    for (int d = 32; d >= 1; d >>= 1) m = fmaxf(m, __shfl_xor(m, d, 64));
    e = (lane < PATCH) ? __expf(al - m) : 0.f;
    float ssum = e;
    #pragma unroll
    for (int d = 32; d >= 1; d >>= 1) ssum += __shfl_xor(ssum, d, 64);
    if (lane < PATCH) attn[t * PATCH + lane] = e / ssum;
}

// ---- Kernel C: out[b,c,h,w] = sum_{i,j} hr[b,c,7h+i,7w+j] * attn[b,h,w,i*7+j]
// block per (b, h, 16-channel group): 8*16*24 = 3072 blocks.
// thread: c_local = tid>>4 (16 channels), w = tid&15. 49 gather loads, full ILP.
__global__ __launch_bounds__(256) void kC(const float* __restrict__ hr,
                                          const float* __restrict__ attn,
                                          float* __restrict__ out) {
    int blk = blockIdx.x;
    int cg  = blk % 24;
    int h   = (blk / 24) % FINALN;
    int b   = blk / (24 * FINALN);

    __shared__ float s_attn[FINALN * PATCH];   // 784 floats
    int tid = threadIdx.x;
    const float* abase = attn + (size_t)(b * 256 + h * 16) * PATCH;
    for (int i = tid; i < FINALN * PATCH; i += 256) s_attn[i] = abase[i];
    __syncthreads();

    int c = cg * 16 + (tid >> 4);
    int w = tid & 15;
    const float* p  = hr + (size_t)(b * DIM + c) * IMG2 + (7 * h) * IMG + 7 * w;
    const float* ap = s_attn + w * PATCH;

    float acc = 0.f;
    #pragma unroll
    for (int i = 0; i < 7; ++i) {
        #pragma unroll
        for (int j = 0; j < 7; ++j) {
            acc = fmaf(p[i * IMG + j], ap[i * 7 + j], acc);
        }
    }
    out[((size_t)(b * DIM + c) * FINALN + h) * FINALN + w] = acc;
}

extern "C" void kernel_launch(void* const* d_in, const int* in_sizes, int n_in,
                              void* d_out, int out_size, void* d_ws, size_t ws_size,
                              hipStream_t stream) {
    const float* hr   = (const float*)d_in[0];
    // d_in[1] = guidance (unused by reference)
    const float* du   = (const float*)d_in[2];
    const float* aw   = (const float*)d_in[3];
    const float* ab   = (const float*)d_in[4];
    const float* wmat = (const float*)d_in[5];
    const float* bmat = (const float*)d_in[6];
    float* out = (float*)d_out;

    float* Wp   = (float*)d_ws;              // 802816 floats (8 * 100352)
    float* attn = Wp + NS * IMG2 * 8;        // 100352.. actually 8*100352 = 802816
    // (attn sized 2048*49 = 100352 floats)

    kA<<<dim3(98, NS), 256, 0, stream>>>((const float4*)hr, aw, (float4*)Wp);
    kB<<<512, 256, 0, stream>>>(Wp, du, ab, wmat, bmat, attn);
    kC<<<3072, 256, 0, stream>>>(hr, attn, out);
}

// Round 3
// 250.727 us; speedup vs baseline: 1.0231x; 1.0194x over previous
//
#include <hip/hip_runtime.h>
#include <cmath>

#define DIM 384
#define IMG 112
#define IMG2 (IMG*IMG)          // 12544
#define FINALN 16
#define PATCH 49
#define DROP_P 0.2f

// Fully fused: one block per output patch (b,h,w). 2048 blocks x 512 threads.
// LDS: patch (384*49 fp32 = 75.3 KB) + aw (1.5 KB) + scratch (1 KB) = 77.8 KB
//   -> 2 blocks/CU (LDS-bound), 16 waves/CU resident. hr read EXACTLY once.
__global__ __launch_bounds__(512) void kFused(const float* __restrict__ hr,
                                              const float* __restrict__ du,
                                              const float* __restrict__ aw,
                                              const float* __restrict__ ab,
                                              const float* __restrict__ wmat,
                                              const float* __restrict__ bmat,
                                              float* __restrict__ out) {
    __shared__ float sp[DIM * PATCH];   // patch, c-major: sp[c*49 + i*7 + j]
    __shared__ float s_aw[DIM];
    __shared__ float s_red[256];        // 196 partials, then 49 attn weights

    int tid = threadIdx.x;

    // XCD-locality swizzle: XCD = blockIdx%8 (round-robin); give each XCD a
    // contiguous range of patch ids so w-adjacent patches (which share 64B
    // sectors of hr rows) live in the same per-XCD L2.
    int id  = blockIdx.x;                 // 0..2047
    int nid = (id & 7) * 256 + (id >> 3);
    int b = nid >> 8;
    int h = (nid >> 4) & 15;
    int w = nid & 15;

    for (int i = tid; i < DIM; i += 512) s_aw[i] = aw[i];

    // ---- stage patch: 2688 runs (c,i) of 7 contiguous floats ----
    const float* base = hr + (size_t)b * DIM * IMG2 + (size_t)(7 * h) * IMG + 7 * w;
    for (int r = tid; r < DIM * 7; r += 512) {
        int c = r / 7;
        int i = r - c * 7;
        const float* p = base + (size_t)c * IMG2 + i * IMG;
        float* d = sp + c * PATCH + i * 7;
        #pragma unroll
        for (int j = 0; j < 7; ++j) d[j] = p[j];
    }
    __syncthreads();

    // ---- logits: 4 groups x 96 channels, threads 0..195 ----
    if (tid < 4 * PATCH) {
        int g = tid / PATCH;            // 0..3
        int p = tid - g * PATCH;        // 0..48
        int c0 = g * 96;
        float acc = 0.f;
        #pragma unroll 8
        for (int c = 0; c < 96; ++c)
            acc = fmaf(sp[(c0 + c) * PATCH + p], s_aw[c0 + c], acc);
        s_red[tid] = acc;
    }
    __syncthreads();

    // ---- wave 0: finalize logits, masked affine, softmax over 49 ----
    if (tid < 64) {
        float al = -1e30f;
        if (tid < PATCH) {
            float logit = s_red[tid] + s_red[PATCH + tid] + s_red[2 * PATCH + tid]
                        + s_red[3 * PATCH + tid] + ab[0];
            float mask = (du[(b << 8) + (h << 4) + w] > DROP_P) ? 1.0f : 0.0f;
            al = fmaf(logit * mask, wmat[tid], bmat[tid]);
        }
        float m = al;
        #pragma unroll
        for (int d = 32; d >= 1; d >>= 1) m = fmaxf(m, __shfl_xor(m, d, 64));
        float e = (tid < PATCH) ? __expf(al - m) : 0.f;
        float s = e;
        #pragma unroll
        for (int d = 32; d >= 1; d >>= 1) s += __shfl_xor(s, d, 64);
        if (tid < PATCH) s_red[tid] = e / s;   // attn
    }
    __syncthreads();

    // ---- output: thread -> channel; sp reads stride-49 (2-way bank = free),
    //      s_red[p] is a broadcast read ----
    if (tid < DIM) {
        const float* pc = sp + tid * PATCH;
        float acc = 0.f;
        #pragma unroll
        for (int p = 0; p < PATCH; ++p)
            acc = fmaf(pc[p], s_red[p], acc);
        out[(((size_t)b * DIM + tid) * FINALN + h) * FINALN + w] = acc;
    }
}

extern "C" void kernel_launch(void* const* d_in, const int* in_sizes, int n_in,
                              void* d_out, int out_size, void* d_ws, size_t ws_size,
                              hipStream_t stream) {
    const float* hr   = (const float*)d_in[0];
    // d_in[1] = guidance (unused by reference)
    const float* du   = (const float*)d_in[2];
    const float* aw   = (const float*)d_in[3];
    const float* ab   = (const float*)d_in[4];
    const float* wmat = (const float*)d_in[5];
    const float* bmat = (const float*)d_in[6];
    float* out = (float*)d_out;

    kFused<<<2048, 512, 0, stream>>>(hr, du, aw, ab, wmat, bmat, out);
}

// Round 4
// 247.724 us; speedup vs baseline: 1.0355x; 1.0121x over previous
//
#include <hip/hip_runtime.h>
#include <cmath>

#define DIM 384
#define IMG 112
#define IMG2 (IMG*IMG)          // 12544
#define FINALN 16
#define PATCH 49
#define DROP_P 0.2f

// Fully fused: one block per output patch (b,h,w). 2048 blocks x 512 threads.
// LDS: patch (384*49 fp32 = 75.3 KB) + aw (1.5 KB) + partials (1.5 KB) = 78.3 KB
//   -> 2 blocks/CU, 16 waves/CU. hr read EXACTLY once (and L3-hot from the
//   harness restore copy). Floor = 154 MB read + 3 MB write.
__global__ __launch_bounds__(512) void kFused(const float* __restrict__ hr,
                                              const float* __restrict__ du,
                                              const float* __restrict__ aw,
                                              const float* __restrict__ ab,
                                              const float* __restrict__ wmat,
                                              const float* __restrict__ bmat,
                                              float* __restrict__ out) {
    __shared__ float sp[DIM * PATCH];   // patch, c-major: sp[c*49 + i*7 + j]
    __shared__ float s_aw[DIM];
    __shared__ float s_red[8 * PATCH];  // 392 logit partials, then 49 attn

    int tid = threadIdx.x;

    // XCD-locality swizzle: each XCD gets a contiguous stripe of patch ids so
    // w-adjacent patches (sharing 64B hr sectors) hit the same per-XCD L2.
    int id  = blockIdx.x;                 // 0..2047
    int nid = (id & 7) * 256 + (id >> 3);
    int b = nid >> 8;
    int h = (nid >> 4) & 15;
    int w = nid & 15;

    // ---- prefetch tiny scalars off the critical path (used by wave 0 later) ----
    float duv = 0.f, abv = 0.f, wv = 0.f, bv = 0.f;
    if (tid < 64) {
        if (tid < PATCH) { wv = wmat[tid]; bv = bmat[tid]; }
        duv = du[(b << 8) + (h << 4) + w];
        abv = ab[0];
    }
    for (int i = tid; i < DIM; i += 512) s_aw[i] = aw[i];

    // ---- stage patch: 2688 runs (c,i) of 7 contiguous floats ----
    const float* base = hr + (size_t)b * DIM * IMG2 + (size_t)(7 * h) * IMG + 7 * w;
    #pragma unroll
    for (int k = 0; k < 6; ++k) {
        int r = tid + k * 512;
        if (r < DIM * 7) {
            int c = r / 7;
            int i = r - c * 7;
            const float* p = base + (size_t)c * IMG2 + i * IMG;
            float* d = sp + c * PATCH + i * 7;
            #pragma unroll
            for (int j = 0; j < 7; ++j) d[j] = p[j];
        }
    }
    __syncthreads();

    // ---- logits: 8 groups x 48 channels, threads 0..391 ----
    if (tid < 8 * PATCH) {
        int g = tid / PATCH;            // 0..7
        int p = tid - g * PATCH;        // 0..48
        int c0 = g * 48;
        float acc = 0.f;
        #pragma unroll 8
        for (int c = 0; c < 48; ++c)
            acc = fmaf(sp[(c0 + c) * PATCH + p], s_aw[c0 + c], acc);
        s_red[tid] = acc;
    }
    __syncthreads();

    // ---- wave 0: finalize logits, masked affine, softmax over 49 ----
    if (tid < 64) {
        float al = -1e30f;
        if (tid < PATCH) {
            float logit = abv;
            #pragma unroll
            for (int g = 0; g < 8; ++g) logit += s_red[g * PATCH + tid];
            float mask = (duv > DROP_P) ? 1.0f : 0.0f;
            al = fmaf(logit * mask, wv, bv);
        }
        float m = al;
        #pragma unroll
        for (int d = 32; d >= 1; d >>= 1) m = fmaxf(m, __shfl_xor(m, d, 64));
        float e = (tid < PATCH) ? __expf(al - m) : 0.f;
        float s = e;
        #pragma unroll
        for (int d = 32; d >= 1; d >>= 1) s += __shfl_xor(s, d, 64);
        if (tid < PATCH) s_red[tid] = e / s;   // attn
    }
    __syncthreads();

    // ---- output: thread -> channel; sp stride-49 across lanes (odd stride =
    //      full bank permutation, conflict-free); s_red[p] broadcast ----
    if (tid < DIM) {
        const float* pc = sp + tid * PATCH;
        float acc = 0.f;
        #pragma unroll
        for (int p = 0; p < PATCH; ++p)
            acc = fmaf(pc[p], s_red[p], acc);
        out[(((size_t)b * DIM + tid) * FINALN + h) * FINALN + w] = acc;
    }
}

extern "C" void kernel_launch(void* const* d_in, const int* in_sizes, int n_in,
                              void* d_out, int out_size, void* d_ws, size_t ws_size,
                              hipStream_t stream) {
    const float* hr   = (const float*)d_in[0];
    // d_in[1] = guidance (unused by reference)
    const float* du   = (const float*)d_in[2];
    const float* aw   = (const float*)d_in[3];
    const float* ab   = (const float*)d_in[4];
    const float* wmat = (const float*)d_in[5];
    const float* bmat = (const float*)d_in[6];
    float* out = (float*)d_out;

    kFused<<<2048, 512, 0, stream>>>(hr, du, aw, ab, wmat, bmat, out);
}